// Round 5
// baseline (1736.767 us; speedup 1.0000x reference)
//
#include <hip/hip_runtime.h>
#include <stdint.h>

#define B_   8
#define T_   1024
#define CIN_ 4096
#define CH_  4096
#define REC_CAP 2048   // max records per (b,t); Binom(4096,0.386) mean 1581, sigma 31 -> +15 sigma

// ---------------- helpers ----------------

// per-byte nonzero -> 0x01, packed
__device__ __forceinline__ uint32_t bytes_nonzero01(uint32_t w) {
  uint32_t t = (w & 0x7F7F7F7Fu) + 0x7F7F7F7Fu;
  t = (t | w) & 0x80808080u;
  return t >> 7;
}

// load 4 consecutive boolean elements (elements idx4*4 .. idx4*4+3) from a
// buffer whose element size is es (1, 2 or 4 bytes); return packed bytes 0/1.
__device__ __forceinline__ uint32_t load4(const void* base, long idx4, int es) {
  if (es == 1) {
    uint32_t w = ((const uint32_t*)base)[idx4];
    return bytes_nonzero01(w);
  } else if (es == 2) {
    uint32_t w0 = ((const uint32_t*)base)[idx4 * 2];
    uint32_t w1 = ((const uint32_t*)base)[idx4 * 2 + 1];
    uint32_t r = 0;
    r |= ((w0 & 0xFFFFu) != 0u) ? 0x00000001u : 0u;
    r |= ((w0 >> 16)     != 0u) ? 0x00000100u : 0u;
    r |= ((w1 & 0xFFFFu) != 0u) ? 0x00010000u : 0u;
    r |= ((w1 >> 16)     != 0u) ? 0x01000000u : 0u;
    return r;
  } else {
    uint4 w = ((const uint4*)base)[idx4];
    uint32_t r = 0;
    r |= (w.x != 0u) ? 0x00000001u : 0u;
    r |= (w.y != 0u) ? 0x00000100u : 0u;
    r |= (w.z != 0u) ? 0x00010000u : 0u;
    r |= (w.w != 0u) ? 0x01000000u : 0u;
    return r;
  }
}

// expand 4 packed 0/1 bytes into 4 int32 0/1
__device__ __forceinline__ uint4 expand01(uint32_t v4) {
  uint4 r = { v4 & 1u, (v4 >> 8) & 1u, (v4 >> 16) & 1u, (v4 >> 24) & 1u };
  return r;
}

// ---------------- kernel 0: encoding detection ----------------
// Round-1 evidence: absmax = float_bits(1.0)-1 => harness uses int32 for bool
// arrays; detect resolves mode=4 via the sW branch. Kept for robustness.
__global__ __launch_bounds__(256) void detect_kernel(const uint32_t* __restrict__ z,
                                                     uint32_t* __restrict__ modep) {
  __shared__ int sB, sH, sW, sL;
  const int n = threadIdx.x;
  if (n == 0) { sB = 1; sH = 1; sW = 1; sL = 0; }
  __syncthreads();
  int okB = 1, okH = 1, okW = 1, low = 0;
  for (int k = 0; k < 16; ++k) {
    uint32_t w = z[n + 256 * k];
    if ((w & 0xFEFEFEFEu) != 0u) okB = 0;                    // bytes in {0,1}?
    uint32_t lo = w & 0xFFFFu, hi = w >> 16;
    if (!((lo == 0u || lo == 0x3F80u) && (hi == 0u || hi == 0x3F80u))) okH = 0;
    if (!(w == 0u || w == 1u)) okW = 0;                      // words in {0,1}?
    if (lo != 0u) low = 1;                                   // f32 has low half 0
  }
  if (!okB) atomicAnd(&sB, 0);
  if (!okH) atomicAnd(&sH, 0);
  if (!okW) atomicAnd(&sW, 0);
  if (low)  atomicOr(&sL, 1);
  __syncthreads();
  if (n == 0) {
    uint32_t mode;
    if (sW)      mode = 4;              // int32 0/1
    else if (sB) mode = 1;              // uint8 bool
    else if (sH) mode = sL ? 2 : 4;     // bf16 : float32
    else         mode = 1;              // fallback (shouldn't happen)
    modep[0] = mode;
  }
}

// ---------------- kernel 1: fan-in index extraction ----------------
// One wave per row; full-row scan, LDS atomic slot counter (order irrelevant).
__global__ __launch_bounds__(256) void extract_kernel(const float* __restrict__ Ain,
                                                      const float* __restrict__ Ah,
                                                      uint32_t* __restrict__ idxin,
                                                      uint32_t* __restrict__ idxh) {
  const int wave = threadIdx.x >> 6;
  const int lane = threadIdx.x & 63;
  const int row  = blockIdx.x * 4 + wave;   // 0..8191
  const float* A;
  uint32_t* outp;
  if (row < 4096) { A = Ain + (long)row * 4096;          outp = idxin + row * 3; }
  else            { A = Ah  + (long)(row - 4096) * 4096; outp = idxh + (row - 4096) * 3; }
  __shared__ int cnt[4];
  if (lane == 0) cnt[wave] = 0;
  __syncthreads();
  const float4* A4 = (const float4*)A;
  #pragma unroll
  for (int it = 0; it < 16; ++it) {
    float4 v = A4[it * 64 + lane];          // cols 4*(it*64+lane) .. +3
    int cbase = (it * 64 + lane) * 4;
    if (v.x != 0.0f) { int p = atomicAdd(&cnt[wave], 1); if (p < 3) outp[p] = cbase;     }
    if (v.y != 0.0f) { int p = atomicAdd(&cnt[wave], 1); if (p < 3) outp[p] = cbase + 1; }
    if (v.z != 0.0f) { int p = atomicAdd(&cnt[wave], 1); if (p < 3) outp[p] = cbase + 2; }
    if (v.w != 0.0f) { int p = atomicAdd(&cnt[wave], 1); if (p < 3) outp[p] = cbase + 3; }
  }
}

// ---------------- kernel 1b: repack idxh into 8B records ----------------
// idxpk[i] = {c0 | c1<<16, c2}  (all indices < 4096, fit u16)
__global__ __launch_bounds__(256) void repack_kernel(const uint32_t* __restrict__ idxh,
                                                     uint2* __restrict__ idxpk) {
  int i = blockIdx.x * 256 + threadIdx.x;
  uint32_t c0 = idxh[i * 3], c1 = idxh[i * 3 + 1], c2 = idxh[i * 3 + 2];
  uint2 r = { c0 | (c1 << 16), c2 };
  idxpk[i] = r;
}

// ---------------- kernel 2: input-OR precompute + z-copy to out ----------------
// in_orb byte [t][i] = bit b set iff (z[b,t,c0]|z[b,t,c1]|z[b,t,c2]).
// Also writes the z-half of out (int32 0/1) — z is only read ONCE total.
__global__ __launch_bounds__(1024) void inor_kernel(const void* __restrict__ z,
                                                    const uint32_t* __restrict__ idxin,
                                                    const uint32_t* __restrict__ modep,
                                                    uint32_t* __restrict__ in_orb,
                                                    uint32_t* __restrict__ out) {
  const int t = blockIdx.x;
  const int n = threadIdx.x;
  const int es = (int)modep[0];
  __shared__ __align__(16) unsigned char zp[4096];   // batch-packed z row
  uint32_t acc = 0;
  #pragma unroll
  for (int b = 0; b < B_; ++b) {
    uint32_t v4 = load4(z, ((long)b * T_ + t) * 1024 + n, es);
    acc |= v4 << b;
    ((uint4*)(out + ((long)b * T_ + t) * 8192))[n] = expand01(v4);
  }
  ((uint32_t*)zp)[n] = acc;
  __syncthreads();
  const uint4* ip = (const uint4*)(idxin + n * 12);  // indices for neurons 4n..4n+3
  uint4 q0 = ip[0], q1 = ip[1], q2 = ip[2];
  uint32_t r0 = (uint32_t)zp[q0.x] | zp[q0.y] | zp[q0.z];
  uint32_t r1 = (uint32_t)zp[q0.w] | zp[q1.x] | zp[q1.y];
  uint32_t r2 = (uint32_t)zp[q1.z] | zp[q1.w] | zp[q2.x];
  uint32_t r3 = (uint32_t)zp[q2.y] | zp[q2.z] | zp[q2.w];
  in_orb[t * 1024 + n] = r0 | (r1 << 8) | (r2 << 16) | (r3 << 24);
}

// ---------------- kernel 2b: active-set record builder ----------------
// For each (b,t): compact list of active neurons (in_or bit set) with their
// fan-in indices: record = {i | c0<<16, c1 | c2<<16}. Order irrelevant.
__global__ __launch_bounds__(256) void build_kernel(const uint32_t* __restrict__ in_orb,
                                                    const uint2* __restrict__ idxpk,
                                                    uint2* __restrict__ rec,
                                                    uint32_t* __restrict__ cnt) {
  const int blk = blockIdx.x;          // b*1024 + t
  const int t = blk & 1023, b = blk >> 10;
  const int tid = threadIdx.x, lane = tid & 63;
  __shared__ int c;
  if (tid == 0) c = 0;
  __syncthreads();
  uint4 w = ((const uint4*)(in_orb + t * 1024))[tid];   // words 4tid..4tid+3
  uint2* recp = rec + (long)blk * REC_CAP;
  uint32_t wd[4] = { w.x, w.y, w.z, w.w };
  #pragma unroll
  for (int k = 0; k < 4; ++k) {
    uint32_t word = wd[k];
    #pragma unroll
    for (int j = 0; j < 4; ++j) {
      int active = (word >> (8 * j + b)) & 1;
      unsigned long long bal = __ballot(active);
      if (bal) {
        int tot = (int)__popcll(bal);
        int base = 0;
        if (lane == 0) base = atomicAdd(&c, tot);
        base = __shfl(base, 0);
        if (active) {
          int rank = (int)__popcll(bal & ((1ull << lane) - 1ull));
          int i = tid * 16 + k * 4 + j;
          uint2 px = idxpk[i];
          int r = base + rank;
          if (r < REC_CAP) {
            uint2 rr = { (uint32_t)i | ((px.x & 0xFFFFu) << 16),
                         (px.x >> 16) | (px.y << 16) };
            recp[r] = rr;
          }
        }
      }
    }
  }
  __syncthreads();
  if (tid == 0) cnt[blk] = (uint32_t)min(c, REC_CAP);
}

// ---------------- kernel 3a: compact scan (records path) ----------------
// 8 blocks (one per batch). Per step: zero next-h (4 b128), each thread
// processes records 2n,2n+1 (coalesced uint4 VMEM load): 3 byte-gathers +
// 1 byte-scatter each; then output expansion from LDS (b128 by 256 lanes).
// DS budget ~145 wave-op-equiv/step vs 280 for the legacy gather-all scan.
__global__ __launch_bounds__(1024) void scan_fat_kernel(const uint2* __restrict__ rec,
                                                        const uint32_t* __restrict__ cnt,
                                                        const void* __restrict__ h0,
                                                        const uint32_t* __restrict__ modep,
                                                        uint32_t* __restrict__ out) {
  const int b = blockIdx.x;
  const int n = threadIdx.x;
  const int es = (int)modep[0];
  __shared__ __align__(16) unsigned char hbuf[2][4096];

  ((uint32_t*)hbuf[0])[n] = load4(h0, (long)b * 1024 + n, es);   // h(-1)

  uint32_t* outh = out + (long)b * T_ * 8192 + 4096;
  const uint2* recb = rec + (long)b * T_ * REC_CAP;
  const uint32_t* cntb = cnt + b * T_;

  // 2-deep prefetch (records stream cold from HBM, ~900cyc latency vs ~840cyc step)
  uint4 zero4 = { 0u, 0u, 0u, 0u };
  uint32_t cA = cntb[0];
  uint32_t cB = cntb[1];
  uint4 rA = zero4, rB = zero4;
  if (2 * n < (int)cA) rA = ((const uint4*)recb)[n];
  if (2 * n < (int)cB) rB = ((const uint4*)(recb + REC_CAP))[n];

  int p = 0;
  for (int t = 0; t < T_; ++t) {
    uint32_t cC = 0; uint4 rC = zero4;
    if (t + 2 < T_) {
      cC = cntb[t + 2];
      if (2 * n < (int)cC) rC = ((const uint4*)(recb + (long)(t + 2) * REC_CAP))[n];
    }
    const unsigned char* hc = &hbuf[p][0];
    unsigned char* hn = &hbuf[p ^ 1][0];

    if (n < 256) ((uint4*)hn)[n] = zero4;          // zero next-h
    __syncthreads();

    if (2 * n < (int)cA) {
      uint32_t i0 = rA.x & 0xFFFFu, c0 = rA.x >> 16;
      uint32_t c1 = rA.y & 0xFFFFu, c2 = rA.y >> 16;
      hn[i0] = (unsigned char)((uint32_t)hc[c0] | hc[c1] | hc[c2]);
      if (2 * n + 1 < (int)cA) {
        uint32_t i1 = rA.z & 0xFFFFu, d0 = rA.z >> 16;
        uint32_t d1 = rA.w & 0xFFFFu, d2 = rA.w >> 16;
        hn[i1] = (unsigned char)((uint32_t)hc[d0] | hc[d1] | hc[d2]);
      }
    }
    __syncthreads();

    if (n < 256) {                                  // output expansion, b128 + 4x uint4 store
      uint4 hb = ((const uint4*)hn)[n];
      uint4* o = (uint4*)(outh + (long)t * 8192 + n * 16);
      o[0] = expand01(hb.x);
      o[1] = expand01(hb.y);
      o[2] = expand01(hb.z);
      o[3] = expand01(hb.w);
    }
    cA = cB; rA = rB;
    cB = cC; rB = rC;
    p ^= 1;
  }
}

// ---------------- kernel 3b: legacy scan (fallback if ws too small) ----------------
__global__ __launch_bounds__(1024) void scan_kernel(const uint32_t* __restrict__ in_orb,
                                                    const uint32_t* __restrict__ idxh,
                                                    const void* __restrict__ h0,
                                                    const uint32_t* __restrict__ modep,
                                                    uint32_t* __restrict__ out) {
  const int b = blockIdx.x;
  const int n = threadIdx.x;
  const int es = (int)modep[0];
  __shared__ __align__(16) unsigned char hbuf[2][4096];

  uint32_t d[4][3];
  {
    const uint4* p = (const uint4*)(idxh + n * 12);
    uint4 q0 = p[0], q1 = p[1], q2 = p[2];
    d[0][0] = q0.x; d[0][1] = q0.y; d[0][2] = q0.z;
    d[1][0] = q0.w; d[1][1] = q1.x; d[1][2] = q1.y;
    d[2][0] = q1.z; d[2][1] = q1.w; d[2][2] = q2.x;
    d[3][0] = q2.y; d[3][1] = q2.z; d[3][2] = q2.w;
  }

  ((uint32_t*)hbuf[0])[n] = load4(h0, (long)b * 1024 + n, es);
  __syncthreads();

  uint32_t* outh = out + (long)b * T_ * 8192 + 4096;

  int p = 0;
  uint32_t inw = in_orb[n];
  for (int t = 0; t < T_; ++t) {
    uint32_t inw_next = (t + 1 < T_) ? in_orb[(t + 1) * 1024 + n] : 0u;
    const unsigned char* hc = &hbuf[p][0];
    unsigned char* hn = &hbuf[p ^ 1][0];

    uint32_t mask = (inw >> b) & 0x01010101u;
    uint32_t out4 = 0;
    if (mask) {
      if (mask & 0x00000001u) {
        uint32_t v = (uint32_t)hc[d[0][0]] | hc[d[0][1]] | hc[d[0][2]];
        out4 |= v;
      }
      if (mask & 0x00000100u) {
        uint32_t v = (uint32_t)hc[d[1][0]] | hc[d[1][1]] | hc[d[1][2]];
        out4 |= v << 8;
      }
      if (mask & 0x00010000u) {
        uint32_t v = (uint32_t)hc[d[2][0]] | hc[d[2][1]] | hc[d[2][2]];
        out4 |= v << 16;
      }
      if (mask & 0x01000000u) {
        uint32_t v = (uint32_t)hc[d[3][0]] | hc[d[3][1]] | hc[d[3][2]];
        out4 |= v << 24;
      }
    }
    ((uint32_t*)hn)[n] = out4;
    ((uint4*)(outh + (long)t * 8192))[n] = expand01(out4);
    __syncthreads();

    inw = inw_next;
    p ^= 1;
  }
}

// ---------------- launch ----------------
extern "C" void kernel_launch(void* const* d_in, const int* in_sizes, int n_in,
                              void* d_out, int out_size, void* d_ws, size_t ws_size,
                              hipStream_t stream) {
  const void*  z   = d_in[0];                 // bool (B,T,CIN) - int32 0/1 (detected)
  const void*  h0  = d_in[1];                 // bool (B,CH)
  const float* Ain = (const float*)d_in[2];   // (CH,CIN) f32
  const float* Ah  = (const float*)d_in[3];   // (CH,CH)  f32
  uint32_t* out = (uint32_t*)d_out;           // int32 0/1

  char* ws = (char*)d_ws;
  // ws layout (bytes):
  //   [0]        mode       256 B
  //   [256]      idx_in     48 KiB
  //   [49408]    idx_h      48 KiB
  //   [98560]    in_orb     4 MiB
  //   [4292864]  idxpk      32 KiB
  //   [4325632]  cnt        32 KiB
  //   [4358400]  records    128 MiB (REC_CAP * 8B * 8192 slabs)   [fat path only]
  uint32_t* modep = (uint32_t*)(ws);
  uint32_t* idxin = (uint32_t*)(ws + 256);
  uint32_t* idxh  = (uint32_t*)(ws + 256 + 49152);
  uint32_t* inorb = (uint32_t*)(ws + 98560);
  uint2*    idxpk = (uint2*)   (ws + 4292864);
  uint32_t* cntp  = (uint32_t*)(ws + 4325632);
  uint2*    recp  = (uint2*)   (ws + 4358400);

  const size_t WS_FAT_NEED = 4358400ull + (size_t)REC_CAP * 8ull * B_ * T_;  // ~138.6 MB
  const bool fat = (ws_size >= WS_FAT_NEED);   // ws_size constant across calls -> graph-stable

  detect_kernel <<<1,    256,  0, stream>>>((const uint32_t*)z, modep);
  extract_kernel<<<2048, 256,  0, stream>>>(Ain, Ah, idxin, idxh);
  inor_kernel   <<<T_,   1024, 0, stream>>>(z, idxin, modep, inorb, out);
  if (fat) {
    repack_kernel  <<<16,       256,  0, stream>>>(idxh, idxpk);
    build_kernel   <<<B_ * T_,  256,  0, stream>>>(inorb, idxpk, recp, cntp);
    scan_fat_kernel<<<B_,       1024, 0, stream>>>(recp, cntp, h0, modep, out);
  } else {
    scan_kernel    <<<B_,       1024, 0, stream>>>(inorb, idxh, h0, modep, out);
  }
}

// Round 6
// 949.800 us; speedup vs baseline: 1.8286x; 1.8286x over previous
//
#include <hip/hip_runtime.h>
#include <stdint.h>

#define B_   8
#define T_   1024
#define CIN_ 4096
#define CH_  4096

// ---------------- helpers ----------------

// per-byte nonzero -> 0x01, packed
__device__ __forceinline__ uint32_t bytes_nonzero01(uint32_t w) {
  uint32_t t = (w & 0x7F7F7F7Fu) + 0x7F7F7F7Fu;
  t = (t | w) & 0x80808080u;
  return t >> 7;
}

// load 4 consecutive boolean elements (elements idx4*4 .. idx4*4+3) from a
// buffer whose element size is es (1, 2 or 4 bytes); return packed bytes 0/1.
__device__ __forceinline__ uint32_t load4(const void* base, long idx4, int es) {
  if (es == 1) {
    uint32_t w = ((const uint32_t*)base)[idx4];
    return bytes_nonzero01(w);
  } else if (es == 2) {
    uint32_t w0 = ((const uint32_t*)base)[idx4 * 2];
    uint32_t w1 = ((const uint32_t*)base)[idx4 * 2 + 1];
    uint32_t r = 0;
    r |= ((w0 & 0xFFFFu) != 0u) ? 0x00000001u : 0u;
    r |= ((w0 >> 16)     != 0u) ? 0x00000100u : 0u;
    r |= ((w1 & 0xFFFFu) != 0u) ? 0x00010000u : 0u;
    r |= ((w1 >> 16)     != 0u) ? 0x01000000u : 0u;
    return r;
  } else {
    uint4 w = ((const uint4*)base)[idx4];
    uint32_t r = 0;
    r |= (w.x != 0u) ? 0x00000001u : 0u;
    r |= (w.y != 0u) ? 0x00000100u : 0u;
    r |= (w.z != 0u) ? 0x00010000u : 0u;
    r |= (w.w != 0u) ? 0x01000000u : 0u;
    return r;
  }
}

// expand 4 packed 0/1 bytes into 4 int32 0/1
__device__ __forceinline__ uint4 expand01(uint32_t v4) {
  uint4 r = { v4 & 1u, (v4 >> 8) & 1u, (v4 >> 16) & 1u, (v4 >> 24) & 1u };
  return r;
}

// ---------------- kernel 1 (+0): fan-in index extraction, detect folded in ----
// Blocks 0..2047: one wave per row; rows 0..4095 = A_input, 4096..8191 = A_hidden.
// Block 2048: encoding detection (round-1 evidence: harness uses int32 for bool
// arrays -> mode=4; kept for robustness). Folding removes one serial launch gap.
__global__ __launch_bounds__(256) void extract_kernel(const float* __restrict__ Ain,
                                                      const float* __restrict__ Ah,
                                                      uint32_t* __restrict__ idxin,
                                                      uint32_t* __restrict__ idxh,
                                                      const uint32_t* __restrict__ z,
                                                      uint32_t* __restrict__ modep) {
  if (blockIdx.x == 2048) {
    // ---- detect (threads 0..255) ----
    __shared__ int sB, sH, sW, sL;
    const int n = threadIdx.x;
    if (n == 0) { sB = 1; sH = 1; sW = 1; sL = 0; }
    __syncthreads();
    int okB = 1, okH = 1, okW = 1, low = 0;
    for (int k = 0; k < 16; ++k) {
      uint32_t w = z[n + 256 * k];
      if ((w & 0xFEFEFEFEu) != 0u) okB = 0;                    // bytes in {0,1}?
      uint32_t lo = w & 0xFFFFu, hi = w >> 16;
      if (!((lo == 0u || lo == 0x3F80u) && (hi == 0u || hi == 0x3F80u))) okH = 0;
      if (!(w == 0u || w == 1u)) okW = 0;                      // words in {0,1}?
      if (lo != 0u) low = 1;                                   // f32 has low half 0
    }
    if (!okB) atomicAnd(&sB, 0);
    if (!okH) atomicAnd(&sH, 0);
    if (!okW) atomicAnd(&sW, 0);
    if (low)  atomicOr(&sL, 1);
    __syncthreads();
    if (n == 0) {
      uint32_t mode;
      if (sW)      mode = 4;              // int32 0/1
      else if (sB) mode = 1;              // uint8 bool
      else if (sH) mode = sL ? 2 : 4;     // bf16 : float32
      else         mode = 1;              // fallback (shouldn't happen)
      modep[0] = mode;
    }
    return;
  }
  // ---- extract: full-row scan, LDS atomic slot counter (order irrelevant) ----
  const int wave = threadIdx.x >> 6;
  const int lane = threadIdx.x & 63;
  const int row  = blockIdx.x * 4 + wave;   // 0..8191
  const float* A;
  uint32_t* outp;
  if (row < 4096) { A = Ain + (long)row * 4096;          outp = idxin + row * 3; }
  else            { A = Ah  + (long)(row - 4096) * 4096; outp = idxh + (row - 4096) * 3; }
  __shared__ int cnt[4];
  if (lane == 0) cnt[wave] = 0;
  __syncthreads();
  const float4* A4 = (const float4*)A;
  #pragma unroll
  for (int it = 0; it < 16; ++it) {
    float4 v = A4[it * 64 + lane];          // cols 4*(it*64+lane) .. +3
    int cbase = (it * 64 + lane) * 4;
    if (v.x != 0.0f) { int p = atomicAdd(&cnt[wave], 1); if (p < 3) outp[p] = cbase;     }
    if (v.y != 0.0f) { int p = atomicAdd(&cnt[wave], 1); if (p < 3) outp[p] = cbase + 1; }
    if (v.z != 0.0f) { int p = atomicAdd(&cnt[wave], 1); if (p < 3) outp[p] = cbase + 2; }
    if (v.w != 0.0f) { int p = atomicAdd(&cnt[wave], 1); if (p < 3) outp[p] = cbase + 3; }
  }
}

// ---------------- kernel 2: input-OR precompute + z-copy to out ----------------
// in_orb byte [t][i] = bit b set iff (z[b,t,c0]|z[b,t,c1]|z[b,t,c2]).
// Also writes the z-half of out (int32 0/1) — z is only read ONCE total.
__global__ __launch_bounds__(1024) void inor_kernel(const void* __restrict__ z,
                                                    const uint32_t* __restrict__ idxin,
                                                    const uint32_t* __restrict__ modep,
                                                    uint32_t* __restrict__ in_orb,
                                                    uint32_t* __restrict__ out) {
  const int t = blockIdx.x;
  const int n = threadIdx.x;
  const int es = (int)modep[0];
  __shared__ __align__(16) unsigned char zp[4096];   // batch-packed z row
  uint32_t acc = 0;
  #pragma unroll
  for (int b = 0; b < B_; ++b) {
    uint32_t v4 = load4(z, ((long)b * T_ + t) * 1024 + n, es);
    acc |= v4 << b;
    ((uint4*)(out + ((long)b * T_ + t) * 8192))[n] = expand01(v4);
  }
  ((uint32_t*)zp)[n] = acc;
  __syncthreads();
  const uint4* ip = (const uint4*)(idxin + n * 12);  // indices for neurons 4n..4n+3
  uint4 q0 = ip[0], q1 = ip[1], q2 = ip[2];
  uint32_t r0 = (uint32_t)zp[q0.x] | zp[q0.y] | zp[q0.z];
  uint32_t r1 = (uint32_t)zp[q0.w] | zp[q1.x] | zp[q1.y];
  uint32_t r2 = (uint32_t)zp[q1.z] | zp[q1.w] | zp[q2.x];
  uint32_t r3 = (uint32_t)zp[q2.y] | zp[q2.z] | zp[q2.w];
  in_orb[t * 1024 + n] = r0 | (r1 << 8) | (r2 << 16) | (r3 << 24);
}

// ---------------- kernel 3: sequential scan (the recurrence) ----------------
// 8 blocks, one per batch. h kept as 4096 bytes in double-buffered LDS.
// DS-pipe issue bound (measured R3/R4): 208 DS wave-ops/step x 5.8cyc + ~400
// conflict cyc = ~1560 cyc/step -> 533 us. Round-5 compacted-records variant
// regressed 2.4x (dependent per-step VMEM loads + scatter conflicts) — keep
// this formulation. Writes the h-half of out directly (idle VMEM pipe).
__global__ __launch_bounds__(1024) void scan_kernel(const uint32_t* __restrict__ in_orb,
                                                    const uint32_t* __restrict__ idxh,
                                                    const void* __restrict__ h0,
                                                    const uint32_t* __restrict__ modep,
                                                    uint32_t* __restrict__ out) {
  const int b = blockIdx.x;
  const int n = threadIdx.x;
  const int es = (int)modep[0];
  __shared__ __align__(16) unsigned char hbuf[2][4096];

  // fan-in indices for neurons 4n..4n+3 -> registers (loop-invariant)
  uint32_t d[4][3];
  {
    const uint4* p = (const uint4*)(idxh + n * 12);
    uint4 q0 = p[0], q1 = p[1], q2 = p[2];
    d[0][0] = q0.x; d[0][1] = q0.y; d[0][2] = q0.z;
    d[1][0] = q0.w; d[1][1] = q1.x; d[1][2] = q1.y;
    d[2][0] = q1.z; d[2][1] = q1.w; d[2][2] = q2.x;
    d[3][0] = q2.y; d[3][1] = q2.z; d[3][2] = q2.w;
  }

  // init h(-1) = h0[b]
  ((uint32_t*)hbuf[0])[n] = load4(h0, (long)b * 1024 + n, es);
  __syncthreads();

  uint32_t* outh = out + (long)b * T_ * 8192 + 4096;  // h-half of out for batch b

  int p = 0;
  uint32_t inw = in_orb[n];   // t = 0 (prefetched)
  for (int t = 0; t < T_; ++t) {
    uint32_t inw_next = (t + 1 < T_) ? in_orb[(t + 1) * 1024 + n] : 0u;
    const unsigned char* hc = &hbuf[p][0];
    unsigned char* hn = &hbuf[p ^ 1][0];

    uint32_t mask = (inw >> b) & 0x01010101u;   // input-OR bits for my 4 neurons
    uint32_t out4 = 0;
    if (mask) {
      if (mask & 0x00000001u) {
        uint32_t v = (uint32_t)hc[d[0][0]] | hc[d[0][1]] | hc[d[0][2]];
        out4 |= v;
      }
      if (mask & 0x00000100u) {
        uint32_t v = (uint32_t)hc[d[1][0]] | hc[d[1][1]] | hc[d[1][2]];
        out4 |= v << 8;
      }
      if (mask & 0x00010000u) {
        uint32_t v = (uint32_t)hc[d[2][0]] | hc[d[2][1]] | hc[d[2][2]];
        out4 |= v << 16;
      }
      if (mask & 0x01000000u) {
        uint32_t v = (uint32_t)hc[d[3][0]] | hc[d[3][1]] | hc[d[3][2]];
        out4 |= v << 24;
      }
    }
    ((uint32_t*)hn)[n] = out4;   // bytes 0/1
    // direct h output: 4 int32 per thread, coalesced uint4 (fire-and-forget)
    ((uint4*)(outh + (long)t * 8192))[n] = expand01(out4);
    __syncthreads();

    inw = inw_next;
    p ^= 1;
  }
}

// ---------------- launch ----------------
extern "C" void kernel_launch(void* const* d_in, const int* in_sizes, int n_in,
                              void* d_out, int out_size, void* d_ws, size_t ws_size,
                              hipStream_t stream) {
  const void*  z   = d_in[0];                 // bool (B,T,CIN) - int32 0/1 (detected)
  const void*  h0  = d_in[1];                 // bool (B,CH)
  const float* Ain = (const float*)d_in[2];   // (CH,CIN) f32
  const float* Ah  = (const float*)d_in[3];   // (CH,CH)  f32
  uint32_t* out = (uint32_t*)d_out;           // int32 0/1

  char* ws = (char*)d_ws;
  // ws layout (bytes): [0] mode | [256] idx_in 48K | [49408] idx_h 48K |
  //                    [98560] in_orb 4MiB   (total ~4.3 MiB)
  uint32_t* modep = (uint32_t*)(ws);
  uint32_t* idxin = (uint32_t*)(ws + 256);
  uint32_t* idxh  = (uint32_t*)(ws + 256 + 49152);
  uint32_t* inorb = (uint32_t*)(ws + 98560);

  extract_kernel<<<2049, 256,  0, stream>>>(Ain, Ah, idxin, idxh,
                                            (const uint32_t*)z, modep);
  inor_kernel   <<<T_,   1024, 0, stream>>>(z, idxin, modep, inorb, out);
  scan_kernel   <<<B_,   1024, 0, stream>>>(inorb, idxh, h0, modep, out);
}